// Round 3
// baseline (727.075 us; speedup 1.0000x reference)
//
#include <hip/hip_runtime.h>

#define NN 50000
#define NE 800000
#define DD 64
#define NB 196   // ceil(NN/256)

// ---- CSR build: histogram of dst ----
__global__ __launch_bounds__(256) void k_hist(const int* __restrict__ dst,
                                              int* __restrict__ cnt) {
    int e = blockIdx.x * 256 + threadIdx.x;
    if (e < NE) atomicAdd(&cnt[dst[e]], 1);
}

// ---- scan pass 1: per-block sums of cnt ----
__global__ __launch_bounds__(256) void k_block_sum(const int* __restrict__ cnt,
                                                   int* __restrict__ bsum) {
    __shared__ int s[256];
    int i = blockIdx.x * 256 + threadIdx.x;
    s[threadIdx.x] = (i < NN) ? cnt[i] : 0;
    __syncthreads();
    for (int o = 128; o > 0; o >>= 1) {
        if (threadIdx.x < o) s[threadIdx.x] += s[threadIdx.x + o];
        __syncthreads();
    }
    if (threadIdx.x == 0) bsum[blockIdx.x] = s[0];
}

// ---- scan pass 2: exclusive scan of NB block sums (single block) ----
__global__ __launch_bounds__(256) void k_scan_bsum(int* __restrict__ bsum) {
    __shared__ int s[256];
    int t = threadIdx.x;
    int v = (t < NB) ? bsum[t] : 0;
    s[t] = v;
    __syncthreads();
    for (int o = 1; o < 256; o <<= 1) {
        int x = (t >= o) ? s[t - o] : 0;
        __syncthreads();
        s[t] += x;
        __syncthreads();
    }
    if (t < NB) bsum[t] = s[t] - v;  // exclusive
}

// ---- scan pass 3: final exclusive offsets; write row_start and cursor ----
__global__ __launch_bounds__(256) void k_scan_final(const int* __restrict__ cnt,
                                                    const int* __restrict__ bsum,
                                                    int* __restrict__ row_start,
                                                    int* __restrict__ cursor) {
    __shared__ int s[256];
    int t = threadIdx.x;
    int i = blockIdx.x * 256 + t;
    int v = (i < NN) ? cnt[i] : 0;
    s[t] = v;
    __syncthreads();
    for (int o = 1; o < 256; o <<= 1) {
        int x = (t >= o) ? s[t - o] : 0;
        __syncthreads();
        s[t] += x;
        __syncthreads();
    }
    int excl = s[t] - v + bsum[blockIdx.x];
    if (i < NN) {
        row_start[i] = excl;
        cursor[i]    = excl;
        if (i == NN - 1) row_start[NN] = excl + v;  // == NE
    }
}

// ---- counting sort: scatter edge ids into dst-sorted order ----
__global__ __launch_bounds__(256) void k_reorder(const int* __restrict__ dst,
                                                 int* __restrict__ cursor,
                                                 int* __restrict__ eid) {
    int e = blockIdx.x * 256 + threadIdx.x;
    if (e < NE) {
        int pos = atomicAdd(&cursor[dst[e]], 1);
        eid[pos] = e;
    }
}

// ---- gather-sum: one wave per node, lane l accumulates feature l ----
__global__ __launch_bounds__(256) void k_gather(const float* __restrict__ ef,
                                                const int* __restrict__ row_start,
                                                const int* __restrict__ eid,
                                                float* __restrict__ nx) {
    int lane = threadIdx.x & 63;
    int n = blockIdx.x * 4 + (threadIdx.x >> 6);
    if (n >= NN) return;
    int beg = row_start[n], end = row_start[n + 1];
    float a0 = 0.f, a1 = 0.f, a2 = 0.f, a3 = 0.f;
    int i = beg;
    for (; i + 3 < end; i += 4) {
        int e0 = eid[i], e1 = eid[i + 1], e2 = eid[i + 2], e3 = eid[i + 3];
        a0 += ef[(long)e0 * DD + lane];
        a1 += ef[(long)e1 * DD + lane];
        a2 += ef[(long)e2 * DD + lane];
        a3 += ef[(long)e3 * DD + lane];
    }
    for (; i < end; ++i) {
        a0 += ef[(long)eid[i] * DD + lane];
    }
    nx[(long)n * DD + lane] = (a0 + a1) + (a2 + a3);
}

// Named-accumulator machinery: NO accumulator array exists anywhere, so
// SROA cannot fail and nothing can be demoted to scratch. 16 named float4
// values = 64 accumulator floats that MUST be register-allocated.
#define ZERO4 make_float4(0.f, 0.f, 0.f, 0.f)

#define ACC_DECL float4 A0=ZERO4,A1=ZERO4,A2=ZERO4,A3=ZERO4,A4=ZERO4,A5=ZERO4, \
    A6=ZERO4,A7=ZERO4,A8=ZERO4,A9=ZERO4,A10=ZERO4,A11=ZERO4,A12=ZERO4, \
    A13=ZERO4,A14=ZERO4,A15=ZERO4

// One j-quad step: ACC[j..j+3] += m0*W[k0][j..] + m1*W[k1][j..] + ...
#define QSTEP(Q, ACC, M0, M1, M2, M3)                                          \
    {                                                                          \
        float4 c0 = w0[Q], c1 = w1[Q], c2 = w2[Q], c3 = w3[Q];                 \
        ACC.x = fmaf(M0, c0.x, fmaf(M1, c1.x, fmaf(M2, c2.x, fmaf(M3, c3.x, ACC.x)))); \
        ACC.y = fmaf(M0, c0.y, fmaf(M1, c1.y, fmaf(M2, c2.y, fmaf(M3, c3.y, ACC.y)))); \
        ACC.z = fmaf(M0, c0.z, fmaf(M1, c1.z, fmaf(M2, c2.z, fmaf(M3, c3.z, ACC.z)))); \
        ACC.w = fmaf(M0, c0.w, fmaf(M1, c1.w, fmaf(M2, c2.w, fmaf(M3, c3.w, ACC.w)))); \
    }

#define QSTEP_ALL(M0, M1, M2, M3)      \
    QSTEP(0,  A0,  M0, M1, M2, M3)     \
    QSTEP(1,  A1,  M0, M1, M2, M3)     \
    QSTEP(2,  A2,  M0, M1, M2, M3)     \
    QSTEP(3,  A3,  M0, M1, M2, M3)     \
    QSTEP(4,  A4,  M0, M1, M2, M3)     \
    QSTEP(5,  A5,  M0, M1, M2, M3)     \
    QSTEP(6,  A6,  M0, M1, M2, M3)     \
    QSTEP(7,  A7,  M0, M1, M2, M3)     \
    QSTEP(8,  A8,  M0, M1, M2, M3)     \
    QSTEP(9,  A9,  M0, M1, M2, M3)     \
    QSTEP(10, A10, M0, M1, M2, M3)     \
    QSTEP(11, A11, M0, M1, M2, M3)     \
    QSTEP(12, A12, M0, M1, M2, M3)     \
    QSTEP(13, A13, M0, M1, M2, M3)     \
    QSTEP(14, A14, M0, M1, M2, M3)     \
    QSTEP(15, A15, M0, M1, M2, M3)

// ---- h_pre = node_x @ W1 : W1 in LDS, named float4 accumulators ----
__global__ __launch_bounds__(256, 2) void k_node_mlp(const float* __restrict__ nx,
                                                     const float* __restrict__ W1,
                                                     float* __restrict__ hp) {
    __shared__ float4 sW[DD * DD / 4];  // 16 KB, row-major float4
    for (int t = threadIdx.x; t < DD * DD / 4; t += 256)
        sW[t] = ((const float4*)W1)[t];
    __syncthreads();

    int n = blockIdx.x * 256 + threadIdx.x;
    if (n >= NN) return;
    const float4* xr = (const float4*)(nx + (long)n * DD);
    ACC_DECL;
    for (int kc = 0; kc < DD / 4; ++kc) {   // rolled: compiler pipelines loads
        float4 x = xr[kc];
        const float4* w0 = &sW[(4 * kc + 0) * (DD / 4)];
        const float4* w1 = &sW[(4 * kc + 1) * (DD / 4)];
        const float4* w2 = &sW[(4 * kc + 2) * (DD / 4)];
        const float4* w3 = &sW[(4 * kc + 3) * (DD / 4)];
        QSTEP_ALL(x.x, x.y, x.z, x.w)
    }
    float4* o = (float4*)(hp + (long)n * DD);
    o[0] = A0;  o[1] = A1;  o[2]  = A2;  o[3]  = A3;
    o[4] = A4;  o[5] = A5;  o[6]  = A6;  o[7]  = A7;
    o[8] = A8;  o[9] = A9;  o[10] = A10; o[11] = A11;
    o[12] = A12; o[13] = A13; o[14] = A14; o[15] = A15;
}

// ---- edge_out = 0.5*(relu(h_pre[src]+h_pre[dst]+b1) @ W2 + b2) ----
// W2 in LDS (uniform-address broadcast reads), named float4 accumulators.
__global__ __launch_bounds__(256, 2) void k_edge_mlp(const float* __restrict__ hp,
                                                     const int* __restrict__ src,
                                                     const int* __restrict__ dst,
                                                     const float* __restrict__ b1,
                                                     const float* __restrict__ W2,
                                                     const float* __restrict__ b2,
                                                     float* __restrict__ out) {
    __shared__ float4 sW[DD * DD / 4];  // 16 KB
    for (int t = threadIdx.x; t < DD * DD / 4; t += 256)
        sW[t] = ((const float4*)W2)[t];
    __syncthreads();

    int e = blockIdx.x * 256 + threadIdx.x;
    if (e >= NE) return;
    int s = src[e], d = dst[e];
    const float4* ps = (const float4*)(hp + (long)s * DD);
    const float4* pd = (const float4*)(hp + (long)d * DD);
    ACC_DECL;
    for (int kc = 0; kc < DD / 4; ++kc) {   // rolled
        float4 a = ps[kc];
        float4 b = pd[kc];
        float4 bb = ((const float4*)b1)[kc];
        float h0 = fmaxf(a.x + b.x + bb.x, 0.f);
        float h1 = fmaxf(a.y + b.y + bb.y, 0.f);
        float h2 = fmaxf(a.z + b.z + bb.z, 0.f);
        float h3 = fmaxf(a.w + b.w + bb.w, 0.f);
        const float4* w0 = &sW[(4 * kc + 0) * (DD / 4)];
        const float4* w1 = &sW[(4 * kc + 1) * (DD / 4)];
        const float4* w2 = &sW[(4 * kc + 2) * (DD / 4)];
        const float4* w3 = &sW[(4 * kc + 3) * (DD / 4)];
        QSTEP_ALL(h0, h1, h2, h3)
    }
    const float4* b2v = (const float4*)b2;
    float4* o = (float4*)(out + (long)e * DD);
#define EPI(Q, ACC)                                     \
    {                                                   \
        float4 bq = b2v[Q];                             \
        float4 r;                                       \
        r.x = 0.5f * (ACC.x + bq.x);                    \
        r.y = 0.5f * (ACC.y + bq.y);                    \
        r.z = 0.5f * (ACC.z + bq.z);                    \
        r.w = 0.5f * (ACC.w + bq.w);                    \
        o[Q] = r;                                       \
    }
    EPI(0, A0)  EPI(1, A1)  EPI(2, A2)   EPI(3, A3)
    EPI(4, A4)  EPI(5, A5)  EPI(6, A6)   EPI(7, A7)
    EPI(8, A8)  EPI(9, A9)  EPI(10, A10) EPI(11, A11)
    EPI(12, A12) EPI(13, A13) EPI(14, A14) EPI(15, A15)
#undef EPI
}

extern "C" void kernel_launch(void* const* d_in, const int* in_sizes, int n_in,
                              void* d_out, int out_size, void* d_ws, size_t ws_size,
                              hipStream_t stream) {
    const float* edge_feat = (const float*)d_in[0];
    const int*   src       = (const int*)d_in[1];
    const int*   dst       = (const int*)d_in[2];
    const float* W1        = (const float*)d_in[3];
    const float* b1        = (const float*)d_in[4];
    const float* W2        = (const float*)d_in[5];
    const float* b2        = (const float*)d_in[6];
    float* out = (float*)d_out;

    char* ws = (char*)d_ws;
    size_t off = 0;
    float* node_x = (float*)(ws + off); off += (size_t)NN * DD * 4;   // 12.8 MB
    float* h_pre  = (float*)(ws + off); off += (size_t)NN * DD * 4;   // 12.8 MB
    int* cnt       = (int*)(ws + off); off += (size_t)NN * 4;
    int* row_start = (int*)(ws + off); off += (size_t)(NN + 1) * 4;
    int* cursor    = (int*)(ws + off); off += (size_t)NN * 4;
    int* bsum      = (int*)(ws + off); off += 256 * 4;
    int* eid       = (int*)(ws + off); off += (size_t)NE * 4;         // 3.2 MB

    hipMemsetAsync(cnt, 0, (size_t)NN * 4, stream);
    k_hist<<<(NE + 255) / 256, 256, 0, stream>>>(dst, cnt);
    k_block_sum<<<NB, 256, 0, stream>>>(cnt, bsum);
    k_scan_bsum<<<1, 256, 0, stream>>>(bsum);
    k_scan_final<<<NB, 256, 0, stream>>>(cnt, bsum, row_start, cursor);
    k_reorder<<<(NE + 255) / 256, 256, 0, stream>>>(dst, cursor, eid);
    k_gather<<<(NN + 3) / 4, 256, 0, stream>>>(edge_feat, row_start, eid, node_x);
    k_node_mlp<<<(NN + 255) / 256, 256, 0, stream>>>(node_x, W1, h_pre);
    k_edge_mlp<<<(NE + 255) / 256, 256, 0, stream>>>(h_pre, src, dst, b1, W2, b2, out);
}

// Round 4
// 556.473 us; speedup vs baseline: 1.3066x; 1.3066x over previous
//
#include <hip/hip_runtime.h>

#define NN 50000
#define NE 800000
#define DD 64
#define NB 196   // ceil(NN/256)
#define EB 64    // rows (edges/nodes) per MLP block tile

// ---- CSR build: histogram of dst ----
__global__ __launch_bounds__(256) void k_hist(const int* __restrict__ dst,
                                              int* __restrict__ cnt) {
    int e = blockIdx.x * 256 + threadIdx.x;
    if (e < NE) atomicAdd(&cnt[dst[e]], 1);
}

// ---- scan pass 1: per-block sums of cnt ----
__global__ __launch_bounds__(256) void k_block_sum(const int* __restrict__ cnt,
                                                   int* __restrict__ bsum) {
    __shared__ int s[256];
    int i = blockIdx.x * 256 + threadIdx.x;
    s[threadIdx.x] = (i < NN) ? cnt[i] : 0;
    __syncthreads();
    for (int o = 128; o > 0; o >>= 1) {
        if (threadIdx.x < o) s[threadIdx.x] += s[threadIdx.x + o];
        __syncthreads();
    }
    if (threadIdx.x == 0) bsum[blockIdx.x] = s[0];
}

// ---- scan pass 2: exclusive scan of NB block sums (single block) ----
__global__ __launch_bounds__(256) void k_scan_bsum(int* __restrict__ bsum) {
    __shared__ int s[256];
    int t = threadIdx.x;
    int v = (t < NB) ? bsum[t] : 0;
    s[t] = v;
    __syncthreads();
    for (int o = 1; o < 256; o <<= 1) {
        int x = (t >= o) ? s[t - o] : 0;
        __syncthreads();
        s[t] += x;
        __syncthreads();
    }
    if (t < NB) bsum[t] = s[t] - v;  // exclusive
}

// ---- scan pass 3: final exclusive offsets; write row_start and cursor ----
__global__ __launch_bounds__(256) void k_scan_final(const int* __restrict__ cnt,
                                                    const int* __restrict__ bsum,
                                                    int* __restrict__ row_start,
                                                    int* __restrict__ cursor) {
    __shared__ int s[256];
    int t = threadIdx.x;
    int i = blockIdx.x * 256 + t;
    int v = (i < NN) ? cnt[i] : 0;
    s[t] = v;
    __syncthreads();
    for (int o = 1; o < 256; o <<= 1) {
        int x = (t >= o) ? s[t - o] : 0;
        __syncthreads();
        s[t] += x;
        __syncthreads();
    }
    int excl = s[t] - v + bsum[blockIdx.x];
    if (i < NN) {
        row_start[i] = excl;
        cursor[i]    = excl;
        if (i == NN - 1) row_start[NN] = excl + v;  // == NE
    }
}

// ---- counting sort: scatter edge ids into dst-sorted order ----
__global__ __launch_bounds__(256) void k_reorder(const int* __restrict__ dst,
                                                 int* __restrict__ cursor,
                                                 int* __restrict__ eid) {
    int e = blockIdx.x * 256 + threadIdx.x;
    if (e < NE) {
        int pos = atomicAdd(&cursor[dst[e]], 1);
        eid[pos] = e;
    }
}

// ---- gather-sum: one wave per node, lane l accumulates feature l ----
__global__ __launch_bounds__(256) void k_gather(const float* __restrict__ ef,
                                                const int* __restrict__ row_start,
                                                const int* __restrict__ eid,
                                                float* __restrict__ nx) {
    int lane = threadIdx.x & 63;
    int n = blockIdx.x * 4 + (threadIdx.x >> 6);
    if (n >= NN) return;
    int beg = row_start[n], end = row_start[n + 1];
    float a0 = 0.f, a1 = 0.f, a2 = 0.f, a3 = 0.f;
    int i = beg;
    for (; i + 3 < end; i += 4) {
        int e0 = eid[i], e1 = eid[i + 1], e2 = eid[i + 2], e3 = eid[i + 3];
        a0 += ef[(long)e0 * DD + lane];
        a1 += ef[(long)e1 * DD + lane];
        a2 += ef[(long)e2 * DD + lane];
        a3 += ef[(long)e3 * DD + lane];
    }
    for (; i < end; ++i) {
        a0 += ef[(long)eid[i] * DD + lane];
    }
    nx[(long)n * DD + lane] = (a0 + a1) + (a2 + a3);
}

#define ZERO4 make_float4(0.f, 0.f, 0.f, 0.f)

// 4x4 outer-product step shared by both GEMM kernels
#define OP16(hv, wv)                                              \
    C0.x = fmaf(hv.x, wv.x, C0.x); C0.y = fmaf(hv.x, wv.y, C0.y); \
    C0.z = fmaf(hv.x, wv.z, C0.z); C0.w = fmaf(hv.x, wv.w, C0.w); \
    C1.x = fmaf(hv.y, wv.x, C1.x); C1.y = fmaf(hv.y, wv.y, C1.y); \
    C1.z = fmaf(hv.y, wv.z, C1.z); C1.w = fmaf(hv.y, wv.w, C1.w); \
    C2.x = fmaf(hv.z, wv.x, C2.x); C2.y = fmaf(hv.z, wv.y, C2.y); \
    C2.z = fmaf(hv.z, wv.z, C2.z); C2.w = fmaf(hv.z, wv.w, C2.w); \
    C3.x = fmaf(hv.w, wv.x, C3.x); C3.y = fmaf(hv.w, wv.y, C3.y); \
    C3.z = fmaf(hv.w, wv.z, C3.z); C3.w = fmaf(hv.w, wv.w, C3.w);

// ---- h_pre = node_x @ W1, block-tiled SGEMM ----
// Block: 64 nodes. Stage X^T (transposed, 16 KB) + W1 (16 KB) in LDS.
// Thread (ty,tx) owns a 4x4 output tile -> 16 acc floats (registers, trivially).
// Per k: ds_read_b128 of 4 rows of X^T (bank quads by ty: conflict-free,
// 16-way broadcast) + ds_read_b128 of 4 cols of W (2-way conflict = free).
__global__ __launch_bounds__(256, 4) void k_node_mlp(const float* __restrict__ nx,
                                                     const float* __restrict__ W1,
                                                     float* __restrict__ hp) {
    __shared__ float sXT[DD][EB];       // [k][row]
    __shared__ float4 sW[DD * DD / 4];  // row-major
    const float4* Wv = (const float4*)W1;
#pragma unroll
    for (int i = 0; i < 4; ++i)
        sW[threadIdx.x + 256 * i] = Wv[threadIdx.x + 256 * i];

    int lane = threadIdx.x & 63;        // row within tile
    int w    = threadIdx.x >> 6;        // wave id: k-chunk group
    long n   = (long)blockIdx.x * EB + lane;
    const float4* px = (const float4*)(nx + n * DD) + 4 * w;
#pragma unroll
    for (int i = 0; i < 4; ++i) {
        float4 a = (n < NN) ? px[i] : ZERO4;
        int k = 16 * w + 4 * i;
        sXT[k + 0][lane] = a.x;
        sXT[k + 1][lane] = a.y;
        sXT[k + 2][lane] = a.z;
        sXT[k + 3][lane] = a.w;
    }
    __syncthreads();

    int tx = threadIdx.x & 15, ty = threadIdx.x >> 4;
    float4 C0 = ZERO4, C1 = ZERO4, C2 = ZERO4, C3 = ZERO4;
#pragma unroll 4
    for (int k = 0; k < DD; ++k) {
        float4 hv = *(const float4*)&sXT[k][4 * ty];
        float4 wv = sW[k * 16 + tx];
        OP16(hv, wv)
    }
    long r0 = (long)blockIdx.x * EB + 4 * ty;
    if (r0 + 0 < NN) ((float4*)(hp + (r0 + 0) * DD))[tx] = C0;
    if (r0 + 1 < NN) ((float4*)(hp + (r0 + 1) * DD))[tx] = C1;
    if (r0 + 2 < NN) ((float4*)(hp + (r0 + 2) * DD))[tx] = C2;
    if (r0 + 3 < NN) ((float4*)(hp + (r0 + 3) * DD))[tx] = C3;
}

// ---- edge_out = 0.5*(relu(h_pre[src]+h_pre[dst]+b1) @ W2 + b2) ----
// Same tiled structure; staging does the gather + relu into H^T.
// NE % EB == 0 -> no guards.
__global__ __launch_bounds__(256, 4) void k_edge_mlp(const float* __restrict__ hp,
                                                     const int* __restrict__ src,
                                                     const int* __restrict__ dst,
                                                     const float* __restrict__ b1,
                                                     const float* __restrict__ W2,
                                                     const float* __restrict__ b2,
                                                     float* __restrict__ out) {
    __shared__ float sHT[DD][EB];       // [k][edge]
    __shared__ float4 sW[DD * DD / 4];
    const float4* Wv = (const float4*)W2;
#pragma unroll
    for (int i = 0; i < 4; ++i)
        sW[threadIdx.x + 256 * i] = Wv[threadIdx.x + 256 * i];

    int lane = threadIdx.x & 63;        // edge within tile
    int w    = threadIdx.x >> 6;        // k-chunk group
    long e   = (long)blockIdx.x * EB + lane;
    int s = src[e], d = dst[e];
    const float4* ps = (const float4*)(hp + (long)s * DD) + 4 * w;
    const float4* pd = (const float4*)(hp + (long)d * DD) + 4 * w;
    const float4* pb = (const float4*)b1 + 4 * w;
#pragma unroll
    for (int i = 0; i < 4; ++i) {
        float4 a = ps[i], b = pd[i], bb = pb[i];
        int k = 16 * w + 4 * i;
        sHT[k + 0][lane] = fmaxf(a.x + b.x + bb.x, 0.f);
        sHT[k + 1][lane] = fmaxf(a.y + b.y + bb.y, 0.f);
        sHT[k + 2][lane] = fmaxf(a.z + b.z + bb.z, 0.f);
        sHT[k + 3][lane] = fmaxf(a.w + b.w + bb.w, 0.f);
    }
    __syncthreads();

    int tx = threadIdx.x & 15, ty = threadIdx.x >> 4;
    float4 C0 = ZERO4, C1 = ZERO4, C2 = ZERO4, C3 = ZERO4;
#pragma unroll 4
    for (int k = 0; k < DD; ++k) {
        float4 hv = *(const float4*)&sHT[k][4 * ty];
        float4 wv = sW[k * 16 + tx];
        OP16(hv, wv)
    }
    float4 bq = ((const float4*)b2)[tx];
    long r0 = (long)blockIdx.x * EB + 4 * ty;
#define EPI(i, C)                                                   \
    {                                                               \
        float4 r;                                                   \
        r.x = 0.5f * (C.x + bq.x); r.y = 0.5f * (C.y + bq.y);       \
        r.z = 0.5f * (C.z + bq.z); r.w = 0.5f * (C.w + bq.w);       \
        ((float4*)(out + (r0 + i) * DD))[tx] = r;                   \
    }
    EPI(0, C0) EPI(1, C1) EPI(2, C2) EPI(3, C3)
#undef EPI
}

extern "C" void kernel_launch(void* const* d_in, const int* in_sizes, int n_in,
                              void* d_out, int out_size, void* d_ws, size_t ws_size,
                              hipStream_t stream) {
    const float* edge_feat = (const float*)d_in[0];
    const int*   src       = (const int*)d_in[1];
    const int*   dst       = (const int*)d_in[2];
    const float* W1        = (const float*)d_in[3];
    const float* b1        = (const float*)d_in[4];
    const float* W2        = (const float*)d_in[5];
    const float* b2        = (const float*)d_in[6];
    float* out = (float*)d_out;

    char* ws = (char*)d_ws;
    size_t off = 0;
    float* node_x = (float*)(ws + off); off += (size_t)NN * DD * 4;   // 12.8 MB
    float* h_pre  = (float*)(ws + off); off += (size_t)NN * DD * 4;   // 12.8 MB
    int* cnt       = (int*)(ws + off); off += (size_t)NN * 4;
    int* row_start = (int*)(ws + off); off += (size_t)(NN + 1) * 4;
    int* cursor    = (int*)(ws + off); off += (size_t)NN * 4;
    int* bsum      = (int*)(ws + off); off += 256 * 4;
    int* eid       = (int*)(ws + off); off += (size_t)NE * 4;         // 3.2 MB

    hipMemsetAsync(cnt, 0, (size_t)NN * 4, stream);
    k_hist<<<(NE + 255) / 256, 256, 0, stream>>>(dst, cnt);
    k_block_sum<<<NB, 256, 0, stream>>>(cnt, bsum);
    k_scan_bsum<<<1, 256, 0, stream>>>(bsum);
    k_scan_final<<<NB, 256, 0, stream>>>(cnt, bsum, row_start, cursor);
    k_reorder<<<(NE + 255) / 256, 256, 0, stream>>>(dst, cursor, eid);
    k_gather<<<(NN + 3) / 4, 256, 0, stream>>>(edge_feat, row_start, eid, node_x);
    k_node_mlp<<<(NN + EB - 1) / EB, 256, 0, stream>>>(node_x, W1, h_pre);
    k_edge_mlp<<<NE / EB, 256, 0, stream>>>(h_pre, src, dst, b1, W2, b2, out);
}

// Round 5
// 517.281 us; speedup vs baseline: 1.4056x; 1.0758x over previous
//
#include <hip/hip_runtime.h>

#define NN 50000
#define NE 800000
#define DD 64
#define NB 196   // ceil(NN/256)
#define EB 64    // rows (edges/nodes) per MLP block tile

// ---- fused histogram + within-node rank: rank[e] = old count of dst[e] ----
__global__ __launch_bounds__(256) void k_build(const int* __restrict__ dst,
                                               int* __restrict__ cnt,
                                               int* __restrict__ rank) {
    int e = blockIdx.x * 256 + threadIdx.x;
    if (e < NE) rank[e] = atomicAdd(&cnt[dst[e]], 1);
}

// ---- scan pass 1: per-block sums of cnt ----
__global__ __launch_bounds__(256) void k_block_sum(const int* __restrict__ cnt,
                                                   int* __restrict__ bsum) {
    __shared__ int s[256];
    int i = blockIdx.x * 256 + threadIdx.x;
    s[threadIdx.x] = (i < NN) ? cnt[i] : 0;
    __syncthreads();
    for (int o = 128; o > 0; o >>= 1) {
        if (threadIdx.x < o) s[threadIdx.x] += s[threadIdx.x + o];
        __syncthreads();
    }
    if (threadIdx.x == 0) bsum[blockIdx.x] = s[0];
}

// ---- scan pass 2 (fused): every block scans the 196 block sums in LDS,
// then produces final exclusive row_start offsets. Saves one launch. ----
__global__ __launch_bounds__(256) void k_scan_final(const int* __restrict__ cnt,
                                                    const int* __restrict__ bsum,
                                                    int* __restrict__ row_start) {
    __shared__ int sb[256];
    __shared__ int s[256];
    int t = threadIdx.x;
    // inclusive scan of block sums (redundant per block; 196 els, cheap)
    sb[t] = (t < NB) ? bsum[t] : 0;
    __syncthreads();
    for (int o = 1; o < 256; o <<= 1) {
        int x = (t >= o) ? sb[t - o] : 0;
        __syncthreads();
        sb[t] += x;
        __syncthreads();
    }
    int boff = (blockIdx.x == 0) ? 0 : sb[blockIdx.x - 1];  // exclusive block offset
    // local scan of this block's 256 counts
    int i = blockIdx.x * 256 + t;
    int v = (i < NN) ? cnt[i] : 0;
    s[t] = v;
    __syncthreads();
    for (int o = 1; o < 256; o <<= 1) {
        int x = (t >= o) ? s[t - o] : 0;
        __syncthreads();
        s[t] += x;
        __syncthreads();
    }
    int excl = s[t] - v + boff;
    if (i < NN) {
        row_start[i] = excl;
        if (i == NN - 1) row_start[NN] = excl + v;  // == NE
    }
}

// ---- place edges into dst-sorted order: NO atomics (rank precomputed) ----
__global__ __launch_bounds__(256) void k_place(const int* __restrict__ dst,
                                               const int* __restrict__ rank,
                                               const int* __restrict__ row_start,
                                               int* __restrict__ eid) {
    int e = blockIdx.x * 256 + threadIdx.x;
    if (e < NE) eid[row_start[dst[e]] + rank[e]] = e;
}

// ---- gather-sum: one wave per node, lane l accumulates feature l.
// 8-deep unroll: 8 independent eid loads then 8 independent 256B gathers
// in flight per wave (old 4-deep chain was latency-limited). ----
__global__ __launch_bounds__(256) void k_gather(const float* __restrict__ ef,
                                                const int* __restrict__ row_start,
                                                const int* __restrict__ eid,
                                                float* __restrict__ nx) {
    int lane = threadIdx.x & 63;
    int n = blockIdx.x * 4 + (threadIdx.x >> 6);
    if (n >= NN) return;
    int beg = row_start[n], end = row_start[n + 1];
    float a0 = 0.f, a1 = 0.f, a2 = 0.f, a3 = 0.f;
    float a4 = 0.f, a5 = 0.f, a6 = 0.f, a7 = 0.f;
    int i = beg;
    for (; i + 7 < end; i += 8) {
        int e0 = eid[i],     e1 = eid[i + 1], e2 = eid[i + 2], e3 = eid[i + 3];
        int e4 = eid[i + 4], e5 = eid[i + 5], e6 = eid[i + 6], e7 = eid[i + 7];
        a0 += ef[(long)e0 * DD + lane];
        a1 += ef[(long)e1 * DD + lane];
        a2 += ef[(long)e2 * DD + lane];
        a3 += ef[(long)e3 * DD + lane];
        a4 += ef[(long)e4 * DD + lane];
        a5 += ef[(long)e5 * DD + lane];
        a6 += ef[(long)e6 * DD + lane];
        a7 += ef[(long)e7 * DD + lane];
    }
    for (; i < end; ++i) {
        a0 += ef[(long)eid[i] * DD + lane];
    }
    nx[(long)n * DD + lane] = ((a0 + a1) + (a2 + a3)) + ((a4 + a5) + (a6 + a7));
}

#define ZERO4 make_float4(0.f, 0.f, 0.f, 0.f)

// 4x4 outer-product step shared by both GEMM kernels
#define OP16(hv, wv)                                              \
    C0.x = fmaf(hv.x, wv.x, C0.x); C0.y = fmaf(hv.x, wv.y, C0.y); \
    C0.z = fmaf(hv.x, wv.z, C0.z); C0.w = fmaf(hv.x, wv.w, C0.w); \
    C1.x = fmaf(hv.y, wv.x, C1.x); C1.y = fmaf(hv.y, wv.y, C1.y); \
    C1.z = fmaf(hv.y, wv.z, C1.z); C1.w = fmaf(hv.y, wv.w, C1.w); \
    C2.x = fmaf(hv.z, wv.x, C2.x); C2.y = fmaf(hv.z, wv.y, C2.y); \
    C2.z = fmaf(hv.z, wv.z, C2.z); C2.w = fmaf(hv.z, wv.w, C2.w); \
    C3.x = fmaf(hv.w, wv.x, C3.x); C3.y = fmaf(hv.w, wv.y, C3.y); \
    C3.z = fmaf(hv.w, wv.z, C3.z); C3.w = fmaf(hv.w, wv.w, C3.w);

// ---- h_pre = node_x @ W1, block-tiled SGEMM ----
// 32 KB LDS/block; launch_bounds(256,5) -> 5 blocks/CU = 160 KB LDS exactly,
// 20 waves/CU. Thread (ty,tx) owns a 4x4 register tile.
__global__ __launch_bounds__(256, 5) void k_node_mlp(const float* __restrict__ nx,
                                                     const float* __restrict__ W1,
                                                     float* __restrict__ hp) {
    __shared__ float sXT[DD][EB];       // [k][row]
    __shared__ float4 sW[DD * DD / 4];  // row-major
    const float4* Wv = (const float4*)W1;
#pragma unroll
    for (int i = 0; i < 4; ++i)
        sW[threadIdx.x + 256 * i] = Wv[threadIdx.x + 256 * i];

    int lane = threadIdx.x & 63;        // row within tile
    int w    = threadIdx.x >> 6;        // wave id: k-chunk group
    long n   = (long)blockIdx.x * EB + lane;
    const float4* px = (const float4*)(nx + n * DD) + 4 * w;
#pragma unroll
    for (int i = 0; i < 4; ++i) {
        float4 a = (n < NN) ? px[i] : ZERO4;
        int k = 16 * w + 4 * i;
        sXT[k + 0][lane] = a.x;
        sXT[k + 1][lane] = a.y;
        sXT[k + 2][lane] = a.z;
        sXT[k + 3][lane] = a.w;
    }
    __syncthreads();

    int tx = threadIdx.x & 15, ty = threadIdx.x >> 4;
    float4 C0 = ZERO4, C1 = ZERO4, C2 = ZERO4, C3 = ZERO4;
#pragma unroll 4
    for (int k = 0; k < DD; ++k) {
        float4 hv = *(const float4*)&sXT[k][4 * ty];
        float4 wv = sW[k * 16 + tx];
        OP16(hv, wv)
    }
    long r0 = (long)blockIdx.x * EB + 4 * ty;
    if (r0 + 0 < NN) ((float4*)(hp + (r0 + 0) * DD))[tx] = C0;
    if (r0 + 1 < NN) ((float4*)(hp + (r0 + 1) * DD))[tx] = C1;
    if (r0 + 2 < NN) ((float4*)(hp + (r0 + 2) * DD))[tx] = C2;
    if (r0 + 3 < NN) ((float4*)(hp + (r0 + 3) * DD))[tx] = C3;
}

// ---- edge_out = 0.5*(relu(h_pre[src]+h_pre[dst]+b1) @ W2 + b2) ----
// Same tiled structure; staging does the gather + relu. NE % EB == 0.
__global__ __launch_bounds__(256, 5) void k_edge_mlp(const float* __restrict__ hp,
                                                     const int* __restrict__ src,
                                                     const int* __restrict__ dst,
                                                     const float* __restrict__ b1,
                                                     const float* __restrict__ W2,
                                                     const float* __restrict__ b2,
                                                     float* __restrict__ out) {
    __shared__ float sHT[DD][EB];       // [k][edge]
    __shared__ float4 sW[DD * DD / 4];
    const float4* Wv = (const float4*)W2;
#pragma unroll
    for (int i = 0; i < 4; ++i)
        sW[threadIdx.x + 256 * i] = Wv[threadIdx.x + 256 * i];

    int lane = threadIdx.x & 63;        // edge within tile
    int w    = threadIdx.x >> 6;        // k-chunk group
    long e   = (long)blockIdx.x * EB + lane;
    int s = src[e], d = dst[e];
    const float4* ps = (const float4*)(hp + (long)s * DD) + 4 * w;
    const float4* pd = (const float4*)(hp + (long)d * DD) + 4 * w;
    const float4* pb = (const float4*)b1 + 4 * w;
#pragma unroll
    for (int i = 0; i < 4; ++i) {
        float4 a = ps[i], b = pd[i], bb = pb[i];
        int k = 16 * w + 4 * i;
        sHT[k + 0][lane] = fmaxf(a.x + b.x + bb.x, 0.f);
        sHT[k + 1][lane] = fmaxf(a.y + b.y + bb.y, 0.f);
        sHT[k + 2][lane] = fmaxf(a.z + b.z + bb.z, 0.f);
        sHT[k + 3][lane] = fmaxf(a.w + b.w + bb.w, 0.f);
    }
    __syncthreads();

    int tx = threadIdx.x & 15, ty = threadIdx.x >> 4;
    float4 C0 = ZERO4, C1 = ZERO4, C2 = ZERO4, C3 = ZERO4;
#pragma unroll 4
    for (int k = 0; k < DD; ++k) {
        float4 hv = *(const float4*)&sHT[k][4 * ty];
        float4 wv = sW[k * 16 + tx];
        OP16(hv, wv)
    }
    float4 bq = ((const float4*)b2)[tx];
    long r0 = (long)blockIdx.x * EB + 4 * ty;
#define EPI(i, C)                                                   \
    {                                                               \
        float4 r;                                                   \
        r.x = 0.5f * (C.x + bq.x); r.y = 0.5f * (C.y + bq.y);       \
        r.z = 0.5f * (C.z + bq.z); r.w = 0.5f * (C.w + bq.w);       \
        ((float4*)(out + (r0 + i) * DD))[tx] = r;                   \
    }
    EPI(0, C0) EPI(1, C1) EPI(2, C2) EPI(3, C3)
#undef EPI
}

extern "C" void kernel_launch(void* const* d_in, const int* in_sizes, int n_in,
                              void* d_out, int out_size, void* d_ws, size_t ws_size,
                              hipStream_t stream) {
    const float* edge_feat = (const float*)d_in[0];
    const int*   src       = (const int*)d_in[1];
    const int*   dst       = (const int*)d_in[2];
    const float* W1        = (const float*)d_in[3];
    const float* b1        = (const float*)d_in[4];
    const float* W2        = (const float*)d_in[5];
    const float* b2        = (const float*)d_in[6];
    float* out = (float*)d_out;

    char* ws = (char*)d_ws;
    size_t off = 0;
    float* node_x = (float*)(ws + off); off += (size_t)NN * DD * 4;   // 12.8 MB
    float* h_pre  = (float*)(ws + off); off += (size_t)NN * DD * 4;   // 12.8 MB
    int* cnt       = (int*)(ws + off); off += (size_t)NN * 4;
    int* row_start = (int*)(ws + off); off += (size_t)(NN + 1) * 4;
    int* bsum      = (int*)(ws + off); off += 256 * 4;
    int* rank      = (int*)(ws + off); off += (size_t)NE * 4;         // 3.2 MB
    int* eid       = (int*)(ws + off); off += (size_t)NE * 4;         // 3.2 MB

    hipMemsetAsync(cnt, 0, (size_t)NN * 4, stream);
    k_build<<<(NE + 255) / 256, 256, 0, stream>>>(dst, cnt, rank);
    k_block_sum<<<NB, 256, 0, stream>>>(cnt, bsum);
    k_scan_final<<<NB, 256, 0, stream>>>(cnt, bsum, row_start);
    k_place<<<(NE + 255) / 256, 256, 0, stream>>>(dst, rank, row_start, eid);
    k_gather<<<(NN + 3) / 4, 256, 0, stream>>>(edge_feat, row_start, eid, node_x);
    k_node_mlp<<<(NN + EB - 1) / EB, 256, 0, stream>>>(node_x, W1, h_pre);
    k_edge_mlp<<<NE / EB, 256, 0, stream>>>(h_pre, src, dst, b1, W2, b2, out);
}